// Round 8
// baseline (104.485 us; speedup 1.0000x reference)
//
#include <hip/hip_runtime.h>
#include <hip/hip_bf16.h>

// CapsuleLayer dynamic routing, MI355X. fp32 in/out.
// C=10, B=128, N=1152, IN=8, OUT=16, 3 routing iters.
//
// v15b (round 18): RESUBMIT of v15 — round 17 bench was an infra failure
//   (container died twice; no compile/correctness verdict, no counters).
//   Theory still untested:
//   G=2, BOTH batches' P in registers. Additive-pipe model: v11/v13/v14 all
//   ~42 us because per-CU pipe demands are ADDITIVE (barriers phase-align
//   blocks -> TCP phase, then DS phase, no cross-overlap): v14: TCP 3.67
//   MB/CU / 64 B/cyc = 24 us + VALU 12 + DS ~6 = 42. Each variant moved work
//   TCP<->DS, sum constant. v15 cuts the SUM: G=2 shares each W line across
//   2 batches with ZERO added DS (v13's mistake): P for both batches = 2x9
//   uint2 = 36 VGPR, static index, full unroll + sched_barrier(0) separators
//   (v13/v14-proven: no hoist balloon, no scratch). TCP/CU = 2.5 blk x
//   (590K W + 2x147K X) = 2.21 MB = 14.4 us; VALU/DS conserved. Expect sum
//   ~34-36 us. W loads i-halved (4 W + 2 X float4 live) to keep peak ~80-85
//   VGPR (6 waves/SIMD; supply 20 w/CU). Falsifier: >=40 us + no spills ->
//   additive model dead; MFMA-priors or concede ~42 us floor.
//
// Structure: 512 thr = 8 waves, one block per (c, b-pair), 640 blocks.
//   Lane l: o-quad q=l&3 (owns o=q*4..+3), row-sub rsub=l>>2; wave w covers
//   rows [w*144,(w+1)*144) in 9 passes of 16. W float4 load = 16 rows x 64 B
//   fully-consumed lines. fp32 accumulation; P bf16x2 in VGPRs (absmax
//   0.0059-0.0078, threshold 0.0172). Logit recomputed per iter from oa
//   (quad butterfly, 2 shfl). Unnormalized softmax (|logit|<~30, fp32-safe).
//   Iter-0 sums fused into priors. XCD-chunked swizzle: 640 = 8x80 bijective.

constexpr int C = 10, B = 128, N = 1152, IN = 8, OUT = 16;
constexpr int THREADS = 512;
constexpr int NW = THREADS / 64;          // 8 waves
constexpr int G = 2;                      // batches per block
constexpr int PASSES = N / (NW * 16);     // 9
constexpr int NBLK = C * (B / G);         // 640
constexpr int NXCD = 8;
constexpr int CHUNK = NBLK / NXCD;        // 80 (640 % 8 == 0: bijective)

__device__ __forceinline__ unsigned packbf(float a, float b) {
    __hip_bfloat162 h = __float22bfloat162_rn(float2{a, b});  // RNE
    return *(unsigned*)&h;
}
__device__ __forceinline__ float bflo(unsigned u) { return __uint_as_float(u << 16); }
__device__ __forceinline__ float bfhi(unsigned u) { return __uint_as_float(u & 0xffff0000u); }

__global__ __launch_bounds__(THREADS)
void caps_route(const float* __restrict__ Xf, const float* __restrict__ Wf,
                float* __restrict__ Of) {
    // combine buffer: [g][w][0..15] = s4 by o, [16] = ssum, [17..19] pad
    __shared__ float lds_c[G][NW][20];                 // 1,280 B

    const int t = threadIdx.x;
    const int l = t & 63;
    const int wid = t >> 6;
    const int q = l & 3;        // o-quad: owns o = q*4 .. q*4+3
    const int rsub = l >> 2;    // row-sub within a pass (0..15)

    // XCD-chunked swizzle: physical bid%8 -> XCD (round-robin dispatch).
    const int bid = blockIdx.x;
    const int blk = (bid & (NXCD - 1)) * CHUNK + (bid >> 3);
    const int c = blk >> 6;     // 64 consecutive logical blocks share c
    const int b0 = (blk & 63) * G;

    // ---- priors: P[g][n][o] = sum_i x[b0+g,n,i] * W[c,n,i,o]
    // BOTH batches -> registers (2x9 uint2 bf16x2, statically indexed).
    // Fully unrolled, sched_barrier(0) separators (no cross-pass hoisting).
    // Fused iter-0 sums (logits all 0 -> uniform softmax -> plain sums).
    uint2 P0r[PASSES], P1r[PASSES];
    float s40[G][4] = {{0.f, 0.f, 0.f, 0.f}, {0.f, 0.f, 0.f, 0.f}};
    const int nbase = wid * (16 * PASSES) + rsub;
    #pragma unroll
    for (int p = 0; p < PASSES; ++p) {
        const int n = nbase + p * 16;
        const float4* wr = (const float4*)(Wf + (size_t)(c * N + n) * (IN * OUT)) + q;
        const float4* x0 = (const float4*)(Xf + (size_t)((b0 + 0) * N + n) * IN);
        const float4* x1 = (const float4*)(Xf + (size_t)((b0 + 1) * N + n) * IN);
        float a0, a1, a2, a3, e0, e1, e2, e3;
        {   // i = 0..3
            const float4 xa0 = x0[0], xa1 = x1[0];
            const float4 u0 = wr[0], u1 = wr[4], u2 = wr[8], u3 = wr[12];
            a0 = xa0.x * u0.x; a1 = xa0.x * u0.y; a2 = xa0.x * u0.z; a3 = xa0.x * u0.w;
            e0 = xa1.x * u0.x; e1 = xa1.x * u0.y; e2 = xa1.x * u0.z; e3 = xa1.x * u0.w;
            a0 = fmaf(xa0.y, u1.x, a0); a1 = fmaf(xa0.y, u1.y, a1);
            a2 = fmaf(xa0.y, u1.z, a2); a3 = fmaf(xa0.y, u1.w, a3);
            e0 = fmaf(xa1.y, u1.x, e0); e1 = fmaf(xa1.y, u1.y, e1);
            e2 = fmaf(xa1.y, u1.z, e2); e3 = fmaf(xa1.y, u1.w, e3);
            a0 = fmaf(xa0.z, u2.x, a0); a1 = fmaf(xa0.z, u2.y, a1);
            a2 = fmaf(xa0.z, u2.z, a2); a3 = fmaf(xa0.z, u2.w, a3);
            e0 = fmaf(xa1.z, u2.x, e0); e1 = fmaf(xa1.z, u2.y, e1);
            e2 = fmaf(xa1.z, u2.z, e2); e3 = fmaf(xa1.z, u2.w, e3);
            a0 = fmaf(xa0.w, u3.x, a0); a1 = fmaf(xa0.w, u3.y, a1);
            a2 = fmaf(xa0.w, u3.z, a2); a3 = fmaf(xa0.w, u3.w, a3);
            e0 = fmaf(xa1.w, u3.x, e0); e1 = fmaf(xa1.w, u3.y, e1);
            e2 = fmaf(xa1.w, u3.z, e2); e3 = fmaf(xa1.w, u3.w, e3);
        }
        {   // i = 4..7
            const float4 xc0 = x0[1], xc1 = x1[1];
            const float4 u0 = wr[16], u1 = wr[20], u2 = wr[24], u3 = wr[28];
            a0 = fmaf(xc0.x, u0.x, a0); a1 = fmaf(xc0.x, u0.y, a1);
            a2 = fmaf(xc0.x, u0.z, a2); a3 = fmaf(xc0.x, u0.w, a3);
            e0 = fmaf(xc1.x, u0.x, e0); e1 = fmaf(xc1.x, u0.y, e1);
            e2 = fmaf(xc1.x, u0.z, e2); e3 = fmaf(xc1.x, u0.w, e3);
            a0 = fmaf(xc0.y, u1.x, a0); a1 = fmaf(xc0.y, u1.y, a1);
            a2 = fmaf(xc0.y, u1.z, a2); a3 = fmaf(xc0.y, u1.w, a3);
            e0 = fmaf(xc1.y, u1.x, e0); e1 = fmaf(xc1.y, u1.y, e1);
            e2 = fmaf(xc1.y, u1.z, e2); e3 = fmaf(xc1.y, u1.w, e3);
            a0 = fmaf(xc0.z, u2.x, a0); a1 = fmaf(xc0.z, u2.y, a1);
            a2 = fmaf(xc0.z, u2.z, a2); a3 = fmaf(xc0.z, u2.w, a3);
            e0 = fmaf(xc1.z, u2.x, e0); e1 = fmaf(xc1.z, u2.y, e1);
            e2 = fmaf(xc1.z, u2.z, e2); e3 = fmaf(xc1.z, u2.w, e3);
            a0 = fmaf(xc0.w, u3.x, a0); a1 = fmaf(xc0.w, u3.y, a1);
            a2 = fmaf(xc0.w, u3.z, a2); a3 = fmaf(xc0.w, u3.w, a3);
            e0 = fmaf(xc1.w, u3.x, e0); e1 = fmaf(xc1.w, u3.y, e1);
            e2 = fmaf(xc1.w, u3.z, e2); e3 = fmaf(xc1.w, u3.w, e3);
        }
        s40[0][0] += a0; s40[0][1] += a1; s40[0][2] += a2; s40[0][3] += a3;
        s40[1][0] += e0; s40[1][1] += e1; s40[1][2] += e2; s40[1][3] += e3;
        P0r[p] = uint2{packbf(a0, a1), packbf(a2, a3)};
        P1r[p] = uint2{packbf(e0, e1), packbf(e2, e3)};
        __builtin_amdgcn_sched_barrier(0);   // no cross-pass load hoisting
    }

    // accumulated output quad-slice (fp32); logit[p] == dot(oa_full16, P[p])
    float oa[G][4] = {{0.f, 0.f, 0.f, 0.f}, {0.f, 0.f, 0.f, 0.f}};

    // ---- dynamic routing ----
    for (int it = 0; it < 3; ++it) {
        float s4[G][4];
        float ssum[G];
        if (it == 0) {
            ssum[0] = ssum[1] = (float)PASSES;
            #pragma unroll
            for (int g = 0; g < G; ++g)
                #pragma unroll
                for (int k = 0; k < 4; ++k) s4[g][k] = s40[g][k];
        } else {
            ssum[0] = ssum[1] = 0.f;
            #pragma unroll
            for (int g = 0; g < G; ++g)
                #pragma unroll
                for (int k = 0; k < 4; ++k) s4[g][k] = 0.f;
            #pragma unroll
            for (int p = 0; p < PASSES; ++p) {
                // g0 and g1 chains independent -> shfl latency overlapped
                const uint2 u = P0r[p];
                const float u0 = bflo(u.x), u1 = bfhi(u.x);
                const float u2 = bflo(u.y), u3 = bfhi(u.y);
                float d0 = oa[0][0] * u0;
                d0 = fmaf(oa[0][1], u1, d0);
                d0 = fmaf(oa[0][2], u2, d0);
                d0 = fmaf(oa[0][3], u3, d0);
                const uint2 v = P1r[p];
                const float v0 = bflo(v.x), v1 = bfhi(v.x);
                const float v2 = bflo(v.y), v3 = bfhi(v.y);
                float d1 = oa[1][0] * v0;
                d1 = fmaf(oa[1][1], v1, d1);
                d1 = fmaf(oa[1][2], v2, d1);
                d1 = fmaf(oa[1][3], v3, d1);
                d0 += __shfl_xor(d0, 1, 64);
                d1 += __shfl_xor(d1, 1, 64);
                d0 += __shfl_xor(d0, 2, 64);
                d1 += __shfl_xor(d1, 2, 64);
                const float e0 = __expf(d0);      // replicated across quad
                const float e1 = __expf(d1);
                ssum[0] += e0;
                ssum[1] += e1;
                s4[0][0] = fmaf(e0, u0, s4[0][0]);
                s4[0][1] = fmaf(e0, u1, s4[0][1]);
                s4[0][2] = fmaf(e0, u2, s4[0][2]);
                s4[0][3] = fmaf(e0, u3, s4[0][3]);
                s4[1][0] = fmaf(e1, v0, s4[1][0]);
                s4[1][1] = fmaf(e1, v1, s4[1][1]);
                s4[1][2] = fmaf(e1, v2, s4[1][2]);
                s4[1][3] = fmaf(e1, v3, s4[1][3]);
            }
        }
        // reduce across the 16 row-subs of the wave (masks 4..32; quad bits
        // 0,1 carry replicas (ssum) / distinct o (s4) -> not summed).
        // 10 independent chains -> shfl latency overlapped by ILP.
        #pragma unroll
        for (int m = 4; m < 64; m <<= 1) {
            #pragma unroll
            for (int g = 0; g < G; ++g) {
                ssum[g] += __shfl_xor(ssum[g], m, 64);
                #pragma unroll
                for (int k = 0; k < 4; ++k) s4[g][k] += __shfl_xor(s4[g][k], m, 64);
            }
        }
        if (l < 4) {  // lane l == quad q: owns o = l*4..l*4+3
            #pragma unroll
            for (int g = 0; g < G; ++g)
                #pragma unroll
                for (int k = 0; k < 4; ++k) lds_c[g][wid][l * 4 + k] = s4[g][k];
        }
        if (l == 0) {
            #pragma unroll
            for (int g = 0; g < G; ++g) lds_c[g][wid][16] = ssum[g];
        }
        __syncthreads();   // A: combine buffer ready

        // all-thread redundant combine + squash (each thread: its own o-quad).
        // lds_c reads: 4 distinct 16B addrs/wave -> 16-lane broadcast, free.
        float ov[G][4];
        #pragma unroll
        for (int g = 0; g < G; ++g) {
            float a0 = 0.f, a1 = 0.f, a2 = 0.f, a3 = 0.f, S = 0.f;
            #pragma unroll
            for (int w = 0; w < NW; ++w) {
                const float4 v = *(const float4*)&lds_c[g][w][q * 4];
                a0 += v.x; a1 += v.y; a2 += v.z; a3 += v.w;
                S += lds_c[g][w][16];
            }
            const float inv = 1.f / S;
            const float s0 = a0 * inv, s1 = a1 * inv;
            const float s2 = a2 * inv, s3 = a3 * inv;
            float r = s0 * s0 + s1 * s1 + s2 * s2 + s3 * s3;
            r += __shfl_xor(r, 1, 64);
            r += __shfl_xor(r, 2, 64);
            const float sc = r / ((1.f + r) * sqrtf(r + 1e-8f));
            ov[g][0] = s0 * sc; ov[g][1] = s1 * sc;
            ov[g][2] = s2 * sc; ov[g][3] = s3 * sc;
        }
        if (it < 2) {
            __syncthreads();   // B: combine reads done before next writes
            #pragma unroll
            for (int g = 0; g < G; ++g)
                #pragma unroll
                for (int k = 0; k < 4; ++k) oa[g][k] += ov[g][k];
        } else if (t < 4) {  // wid==0, rsub==0, q==t: write final outputs
            #pragma unroll
            for (int g = 0; g < G; ++g)
                #pragma unroll
                for (int k = 0; k < 4; ++k)
                    Of[((size_t)c * B + b0 + g) * OUT + q * 4 + k] = ov[g][k];
        }
    }
}

extern "C" void kernel_launch(void* const* d_in, const int* in_sizes, int n_in,
                              void* d_out, int out_size, void* d_ws, size_t ws_size,
                              hipStream_t stream) {
    const float* X = (const float*)d_in[0];   // [B,N,IN] fp32
    const float* W = (const float*)d_in[1];   // [C,N,IN,OUT] fp32
    float* O = (float*)d_out;                 // [C,B,OUT] fp32
    hipLaunchKernelGGL(caps_route, dim3(NBLK), dim3(THREADS), 0, stream, X, W, O);
}